// Round 1
// baseline (20.491 us; speedup 1.0000x reference)
//
#include <hip/hip_runtime.h>
#include <hip/hip_bf16.h>

// CRPS loss:
//   crps(p) = (1/N) sum_i |x_i - y| - (1/N^2) sum_{i<j} |x_i - x_j|
//   out = mean_p crps(p)
// N = 20 ensemble members (compile-time), P = B*C*D*H*W spatial points.

constexpr int N_ENS = 20;

__global__ __launch_bounds__(256) void crps_partial_kernel(
    const float* __restrict__ fc,   // (N_ENS, P)
    const float* __restrict__ obs,  // (P)
    float* __restrict__ partial,    // (gridDim.x)
    int P)
{
    const int stride = gridDim.x * blockDim.x;
    float local = 0.0f;

    for (int p = blockIdx.x * blockDim.x + threadIdx.x; p < P; p += stride) {
        float x[N_ENS];
        #pragma unroll
        for (int i = 0; i < N_ENS; ++i) {
            x[i] = fc[(size_t)i * (size_t)P + (size_t)p];
        }
        const float y = obs[p];

        float t1 = 0.0f;
        #pragma unroll
        for (int i = 0; i < N_ENS; ++i) t1 += fabsf(x[i] - y);

        float t2 = 0.0f;
        #pragma unroll
        for (int i = 0; i < N_ENS; ++i) {
            #pragma unroll
            for (int j = i + 1; j < N_ENS; ++j) {
                t2 += fabsf(x[i] - x[j]);
            }
        }

        // first_term = t1/N ; second_term = (1/(2N^2)) * (2*t2) = t2/N^2
        local += t1 * (1.0f / N_ENS) - t2 * (1.0f / (N_ENS * N_ENS));
    }

    // wave (64-lane) reduction
    #pragma unroll
    for (int off = 32; off > 0; off >>= 1)
        local += __shfl_down(local, off, 64);

    __shared__ float wsum[4];  // 256 threads = 4 waves
    const int lane = threadIdx.x & 63;
    const int wid  = threadIdx.x >> 6;
    if (lane == 0) wsum[wid] = local;
    __syncthreads();
    if (threadIdx.x == 0) {
        float s = wsum[0] + wsum[1] + wsum[2] + wsum[3];
        partial[blockIdx.x] = s;
    }
}

__global__ __launch_bounds__(256) void crps_reduce_kernel(
    const float* __restrict__ partial,
    int nblocks,
    float* __restrict__ out,
    float inv_total)
{
    double s = 0.0;
    for (int i = threadIdx.x; i < nblocks; i += blockDim.x)
        s += (double)partial[i];

    #pragma unroll
    for (int off = 32; off > 0; off >>= 1)
        s += __shfl_down(s, off, 64);

    __shared__ double wsum[4];
    const int lane = threadIdx.x & 63;
    const int wid  = threadIdx.x >> 6;
    if (lane == 0) wsum[wid] = s;
    __syncthreads();
    if (threadIdx.x == 0) {
        double tot = wsum[0] + wsum[1] + wsum[2] + wsum[3];
        out[0] = (float)(tot * (double)inv_total);
    }
}

extern "C" void kernel_launch(void* const* d_in, const int* in_sizes, int n_in,
                              void* d_out, int out_size, void* d_ws, size_t ws_size,
                              hipStream_t stream) {
    const float* fc  = (const float*)d_in[0];
    const float* obs = (const float*)d_in[1];
    float* out = (float*)d_out;

    const int P = in_sizes[1];                 // B*C*D*H*W = 524288
    // in_sizes[0] / P == N_ENS == 20 (fixed problem shape)

    const int block = 256;
    int nblocks = (P + block - 1) / block;     // 2048 for P=524288
    if (nblocks > 4096) nblocks = 4096;        // ws safety cap; grid-stride covers rest

    float* partial = (float*)d_ws;             // nblocks floats

    crps_partial_kernel<<<nblocks, block, 0, stream>>>(fc, obs, partial, P);
    crps_reduce_kernel<<<1, block, 0, stream>>>(partial, nblocks, out, 1.0f / (float)P);
}

// Round 2
// 19.334 us; speedup vs baseline: 1.0599x; 1.0599x over previous
//
#include <hip/hip_runtime.h>
#include <hip/hip_bf16.h>

// CRPS loss:
//   crps(p) = (1/N) sum_i |x_i - y| - (1/N^2) sum_{i<j} |x_i - x_j|
//   out = mean_p crps(p)
// N = 20 ensemble members (compile-time), P = B*C*D*H*W spatial points.
// Memory-bound: 44 MB traffic -> ~7 us floor. Vectorize to 16 B/lane loads.

constexpr int N_ENS = 20;

typedef float f4 __attribute__((ext_vector_type(4)));

__global__ __launch_bounds__(256) void crps_partial_v4(
    const f4* __restrict__ fc,    // (N_ENS, nv) in float4 units
    const f4* __restrict__ obs,   // (nv)
    const float* __restrict__ fc_s,   // scalar view for tail
    const float* __restrict__ obs_s,
    float* __restrict__ partial,  // (gridDim.x)
    int nv, int P)
{
    const int stride = gridDim.x * blockDim.x;
    const int gtid = blockIdx.x * blockDim.x + threadIdx.x;
    float local = 0.0f;

    for (int v = gtid; v < nv; v += stride) {
        f4 x[N_ENS];
        #pragma unroll
        for (int i = 0; i < N_ENS; ++i)
            x[i] = fc[(size_t)i * (size_t)nv + (size_t)v];
        const f4 y = obs[v];

        #pragma unroll
        for (int c = 0; c < 4; ++c) {
            float xc[N_ENS];
            #pragma unroll
            for (int i = 0; i < N_ENS; ++i) xc[i] = x[i][c];
            const float yc = y[c];

            float t1 = 0.0f;
            #pragma unroll
            for (int i = 0; i < N_ENS; ++i) t1 += fabsf(xc[i] - yc);

            float t2 = 0.0f;
            #pragma unroll
            for (int i = 0; i < N_ENS; ++i) {
                #pragma unroll
                for (int j = i + 1; j < N_ENS; ++j)
                    t2 += fabsf(xc[i] - xc[j]);
            }
            local += t1 * (1.0f / N_ENS) - t2 * (1.0f / (N_ENS * N_ENS));
        }
    }

    // scalar tail (P not divisible by 4) — P=524288 -> no-op
    for (int p = 4 * nv + gtid; p < P; p += stride) {
        float xc[N_ENS];
        #pragma unroll
        for (int i = 0; i < N_ENS; ++i) xc[i] = fc_s[(size_t)i * (size_t)P + p];
        const float yc = obs_s[p];
        float t1 = 0.0f, t2 = 0.0f;
        #pragma unroll
        for (int i = 0; i < N_ENS; ++i) t1 += fabsf(xc[i] - yc);
        #pragma unroll
        for (int i = 0; i < N_ENS; ++i) {
            #pragma unroll
            for (int j = i + 1; j < N_ENS; ++j)
                t2 += fabsf(xc[i] - xc[j]);
        }
        local += t1 * (1.0f / N_ENS) - t2 * (1.0f / (N_ENS * N_ENS));
    }

    // wave (64-lane) reduction
    #pragma unroll
    for (int off = 32; off > 0; off >>= 1)
        local += __shfl_down(local, off, 64);

    __shared__ float wsum[4];  // 256 threads = 4 waves
    const int lane = threadIdx.x & 63;
    const int wid  = threadIdx.x >> 6;
    if (lane == 0) wsum[wid] = local;
    __syncthreads();
    if (threadIdx.x == 0)
        partial[blockIdx.x] = wsum[0] + wsum[1] + wsum[2] + wsum[3];
}

__global__ __launch_bounds__(256) void crps_reduce_kernel(
    const float* __restrict__ partial,
    int nblocks,
    float* __restrict__ out,
    float inv_total)
{
    double s = 0.0;
    for (int i = threadIdx.x; i < nblocks; i += blockDim.x)
        s += (double)partial[i];

    #pragma unroll
    for (int off = 32; off > 0; off >>= 1)
        s += __shfl_down(s, off, 64);

    __shared__ double wsum[4];
    const int lane = threadIdx.x & 63;
    const int wid  = threadIdx.x >> 6;
    if (lane == 0) wsum[wid] = s;
    __syncthreads();
    if (threadIdx.x == 0) {
        double tot = wsum[0] + wsum[1] + wsum[2] + wsum[3];
        out[0] = (float)(tot * (double)inv_total);
    }
}

extern "C" void kernel_launch(void* const* d_in, const int* in_sizes, int n_in,
                              void* d_out, int out_size, void* d_ws, size_t ws_size,
                              hipStream_t stream) {
    const float* fc  = (const float*)d_in[0];
    const float* obs = (const float*)d_in[1];
    float* out = (float*)d_out;

    const int P  = in_sizes[1];   // B*C*D*H*W = 524288
    const int nv = P >> 2;        // float4 count per ensemble row = 131072

    const int block = 256;
    int nblocks = (nv + block - 1) / block;   // 512
    if (nblocks < 1) nblocks = 1;
    if (nblocks > 4096) nblocks = 4096;       // ws safety cap; grid-stride covers rest

    float* partial = (float*)d_ws;            // nblocks floats

    crps_partial_v4<<<nblocks, block, 0, stream>>>(
        (const f4*)fc, (const f4*)obs, fc, obs, partial, nv, P);
    crps_reduce_kernel<<<1, block, 0, stream>>>(partial, nblocks, out, 1.0f / (float)P);
}